// Round 1
// baseline (339.608 us; speedup 1.0000x reference)
//
#include <hip/hip_runtime.h>
#include <hip/hip_bf16.h>
#include <cstddef>

#define NHEADS 9
#define D 32
#define SQ 4096

typedef __attribute__((ext_vector_type(8))) short bf16x8;
typedef __attribute__((ext_vector_type(4))) float f32x4;

__device__ __forceinline__ unsigned int f2bf(float f) {
    // round-to-nearest-even f32 -> bf16 bits
    unsigned int u = __float_as_uint(f);
    u += 0x7fffu + ((u >> 16) & 1u);
    return u >> 16;
}

// ---------------------------------------------------------------------------
// Prep: bilinear upsample (32->64, half-pixel) + 1x1 convs -> Q,K,V (bf16) + t
// Q: [bh][n][d]  (d contiguous, A/B-fragment friendly)
// K: [bh][m][d]
// V: [bh][d][m]  (m contiguous)
// ---------------------------------------------------------------------------
__global__ __launch_bounds__(256) void prep_kernel(
    const float* __restrict__ x2, const float* __restrict__ x1,
    const float* __restrict__ feat1,
    const float* __restrict__ Wq, const float* __restrict__ bq,
    const float* __restrict__ Wk, const float* __restrict__ bk,
    const float* __restrict__ Wv, const float* __restrict__ bv,
    const float* __restrict__ Wt, const float* __restrict__ bt,
    unsigned short* __restrict__ Qb, unsigned short* __restrict__ Kb,
    unsigned short* __restrict__ Vb, float* __restrict__ tbuf)
{
    int tid = blockIdx.x * blockDim.x + threadIdx.x;   // 0 .. 2*9*4096-1
    int n  = tid & (SQ - 1);
    int bh = tid >> 12;
    int h  = bh % NHEADS;
    int b  = bh / NHEADS;

    float xs0 = x2[((size_t)b * 3 + 0) * SQ + n];
    float xs1 = x2[((size_t)b * 3 + 1) * SQ + n];
    float xs2 = x2[((size_t)b * 3 + 2) * SQ + n];
    float ys0 = x1[((size_t)b * 3 + 0) * SQ + n];
    float ys1 = x1[((size_t)b * 3 + 1) * SQ + n];
    float ys2 = x1[((size_t)b * 3 + 2) * SQ + n];

    // bilinear upsample coords: src = i*0.5 - 0.25 (half-pixel, align_corners=False)
    int yy = n >> 6, xx = n & 63;
    int jy = yy >> 1, jx = xx >> 1;
    int j0, j1, i0, i1; float wy0, wy1, wx0, wx1;
    if (yy & 1) { j0 = jy; j1 = (jy < 31) ? jy + 1 : 31; wy0 = 0.75f; wy1 = 0.25f; }
    else        { j0 = (jy > 0) ? jy - 1 : 0; j1 = jy;   wy0 = 0.25f; wy1 = 0.75f; }
    if (xx & 1) { i0 = jx; i1 = (jx < 31) ? jx + 1 : 31; wx0 = 0.75f; wx1 = 0.25f; }
    else        { i0 = (jx > 0) ? jx - 1 : 0; i1 = jx;   wx0 = 0.25f; wx1 = 0.75f; }

    float fu[4];
#pragma unroll
    for (int c = 0; c < 4; ++c) {
        const float* f = feat1 + ((size_t)b * 4 + c) * 1024;
        fu[c] = wy0 * (wx0 * f[j0 * 32 + i0] + wx1 * f[j0 * 32 + i1]) +
                wy1 * (wx0 * f[j1 * 32 + i0] + wx1 * f[j1 * 32 + i1]);
    }

    unsigned int qp[16], kp[16];
    float tacc = bt[0];
    int hd0 = h * D;
#pragma unroll
    for (int d = 0; d < D; ++d) {
        int hd = hd0 + d;
        float q = bq[hd] + Wq[hd * 3] * xs0 + Wq[hd * 3 + 1] * xs1 + Wq[hd * 3 + 2] * xs2;
        float k = bk[hd] + Wk[hd * 3] * ys0 + Wk[hd * 3 + 1] * ys1 + Wk[hd * 3 + 2] * ys2;
        float v = bv[hd] + Wv[hd * 4] * fu[0] + Wv[hd * 4 + 1] * fu[1] +
                  Wv[hd * 4 + 2] * fu[2] + Wv[hd * 4 + 3] * fu[3];
        tacc += q * Wt[d];      // threshold from f32 Q, like the reference
        unsigned int qb_ = f2bf(q), kb_ = f2bf(k);
        if (d & 1) { qp[d >> 1] |= qb_ << 16; kp[d >> 1] |= kb_ << 16; }
        else       { qp[d >> 1]  = qb_;       kp[d >> 1]  = kb_; }
        Vb[((size_t)bh * D + d) * SQ + n] = (unsigned short)f2bf(v);
    }
    tbuf[(size_t)bh * SQ + n] = tacc;

    uint4* qdst = (uint4*)(Qb + ((size_t)bh * SQ + n) * D);
    uint4* kdst = (uint4*)(Kb + ((size_t)bh * SQ + n) * D);
#pragma unroll
    for (int w = 0; w < 4; ++w) {
        qdst[w] = make_uint4(qp[4 * w], qp[4 * w + 1], qp[4 * w + 2], qp[4 * w + 3]);
        kdst[w] = make_uint4(kp[4 * w], kp[4 * w + 1], kp[4 * w + 2], kp[4 * w + 3]);
    }
}

// ---------------------------------------------------------------------------
// Attention: per block = one (b,h) x 64 query rows (4 waves x 16 rows).
// Per 32-m chunk: QK via 2x mfma_16x16x32_bf16, relu((sim-t)/3000),
// C-layout -> A-layout via wave-private LDS, PV via 2x mfma (two d-halves).
// Epilogue fuses Wp projection (288->4) with atomicAdd into of[b][o][n].
// ---------------------------------------------------------------------------
__global__ __launch_bounds__(256) void attn_kernel(
    const unsigned short* __restrict__ Qb,
    const unsigned short* __restrict__ Kb,
    const unsigned short* __restrict__ Vb,
    const float* __restrict__ tbuf,
    const float* __restrict__ Wp,
    float* __restrict__ of)
{
    __shared__ __align__(16) unsigned short attn_s[4][16][32];  // per-wave [n][m]
    __shared__ float of_s[4][64];                               // [o][n_local]

    const int bh   = blockIdx.y;          // 0..17
    const int h    = bh % NHEADS;
    const int b    = bh / NHEADS;
    const int n0   = blockIdx.x * 64;
    const int tid  = threadIdx.x;
    const int wave = tid >> 6;
    const int lane = tid & 63;
    const int l15  = lane & 15;
    const int quad = lane >> 4;

    of_s[tid >> 6][tid & 63] = 0.0f;
    __syncthreads();

    const int nw = n0 + wave * 16;

    // A1 fragment: Q[n=l15][d=quad*8+j], resident all loop
    bf16x8 a_q = *(const bf16x8*)(Qb + ((size_t)bh * SQ + nw + l15) * D + quad * 8);

    float tt[4];
#pragma unroll
    for (int r = 0; r < 4; ++r)
        tt[r] = tbuf[(size_t)bh * SQ + nw + quad * 4 + r] * (1.0f / 3000.0f);

    const float s1 = 5.892556509887896e-05f;   // 1/(sqrt(32)*3000)

    const unsigned short* Kbh = Kb + (size_t)bh * SQ * D;
    const unsigned short* Vbh = Vb + (size_t)bh * D * SQ;
    const unsigned short* kpp = Kbh + l15 * D + quad * 8;
    const unsigned short* vpp = Vbh + (size_t)l15 * SQ + quad * 8;

    f32x4 acc_lo = {0.f, 0.f, 0.f, 0.f};
    f32x4 acc_hi = {0.f, 0.f, 0.f, 0.f};
    unsigned short* as_w = &attn_s[wave][0][0];

    for (int mc = 0; mc < SQ; mc += 32) {
        // B1 fragments: K[d=quad*8+j][m], two 16-m tiles
        bf16x8 b1a = *(const bf16x8*)(kpp + (size_t)mc * D);
        bf16x8 b1b = *(const bf16x8*)(kpp + (size_t)(mc + 16) * D);
        f32x4 z = {0.f, 0.f, 0.f, 0.f};
        f32x4 sa = __builtin_amdgcn_mfma_f32_16x16x32_bf16(a_q, b1a, z, 0, 0, 0);
        f32x4 sb = __builtin_amdgcn_mfma_f32_16x16x32_bf16(a_q, b1b, z, 0, 0, 0);
        // C/D: col=lane&15 (m), row=quad*4+reg (n). relu((sim - t)/3000) -> LDS [n][m]
#pragma unroll
        for (int r = 0; r < 4; ++r) {
            float va = fmaxf(fmaf(sa[r], s1, -tt[r]), 0.0f);
            float vb = fmaxf(fmaf(sb[r], s1, -tt[r]), 0.0f);
            as_w[(quad * 4 + r) * 32 + l15]      = (unsigned short)f2bf(va);
            as_w[(quad * 4 + r) * 32 + 16 + l15] = (unsigned short)f2bf(vb);
        }
        // A2 fragment: attn[n=l15][m=quad*8+j]  (wave-private LDS, in-order DS pipe)
        bf16x8 a2 = *(const bf16x8*)(as_w + l15 * 32 + quad * 8);
        // B2 fragments: V[m=quad*8+j][d], d-halves 0..15 / 16..31
        bf16x8 b2lo = *(const bf16x8*)(vpp + mc);
        bf16x8 b2hi = *(const bf16x8*)(vpp + (size_t)16 * SQ + mc);
        acc_lo = __builtin_amdgcn_mfma_f32_16x16x32_bf16(a2, b2lo, acc_lo, 0, 0, 0);
        acc_hi = __builtin_amdgcn_mfma_f32_16x16x32_bf16(a2, b2hi, acc_hi, 0, 0, 0);
    }

    // out[n=quad*4+r][d=l15 (+16)] -> project with Wp[o][h*32+d], reduce in LDS
    const int hd_lo = h * D + l15;
    const int hd_hi = hd_lo + 16;
#pragma unroll
    for (int r = 0; r < 4; ++r) {
        int nl = wave * 16 + quad * 4 + r;
#pragma unroll
        for (int o = 0; o < 4; ++o) {
            float c = acc_lo[r] * Wp[o * 288 + hd_lo] + acc_hi[r] * Wp[o * 288 + hd_hi];
            atomicAdd(&of_s[o][nl], c);
        }
    }
    __syncthreads();
    {
        int o = tid >> 6, nl = tid & 63;
        atomicAdd(&of[((size_t)b * 4 + o) * SQ + n0 + nl], of_s[o][nl]);
    }
}

// ---------------------------------------------------------------------------
// Final: 2x2-mean downsample (exact for half-pixel linear, antialias=False)
// + bias + residual; writes (final_feat, out_feat_down) concatenated.
// ---------------------------------------------------------------------------
__global__ void final_kernel(const float* __restrict__ of,
                             const float* __restrict__ sff,
                             const float* __restrict__ bp,
                             float* __restrict__ dout)
{
    int tid = blockIdx.x * blockDim.x + threadIdx.x;  // 0..8191
    if (tid >= 8192) return;
    int i  = tid & 31;
    int jj = (tid >> 5) & 31;
    int bo = tid >> 10;          // b*4+o
    int o  = bo & 3;
    const float* src = of + (size_t)bo * SQ;
    int y = jj * 2, x = i * 2;
    float dval = 0.25f * (src[y * 64 + x] + src[y * 64 + x + 1] +
                          src[(y + 1) * 64 + x] + src[(y + 1) * 64 + x + 1]) + bp[o];
    dout[tid]        = sff[tid] + dval;   // final_feat
    dout[8192 + tid] = dval;              // out_feat_down
}

extern "C" void kernel_launch(void* const* d_in, const int* in_sizes, int n_in,
                              void* d_out, int out_size, void* d_ws, size_t ws_size,
                              hipStream_t stream)
{
    const float* second_frame = (const float*)d_in[0];
    const float* first_frame  = (const float*)d_in[1];
    const float* sff          = (const float*)d_in[2];
    const float* ffa          = (const float*)d_in[3];
    const float* Wq = (const float*)d_in[4];
    const float* bq = (const float*)d_in[5];
    const float* Wk = (const float*)d_in[6];
    const float* bk = (const float*)d_in[7];
    const float* Wv = (const float*)d_in[8];
    const float* bv = (const float*)d_in[9];
    const float* Wp = (const float*)d_in[10];
    const float* bp = (const float*)d_in[11];
    const float* Wt = (const float*)d_in[12];
    const float* bt = (const float*)d_in[13];
    float* out = (float*)d_out;

    char* ws = (char*)d_ws;
    const size_t QKV = (size_t)2 * NHEADS * SQ * D * sizeof(unsigned short); // 4,718,592 B each
    unsigned short* Qb = (unsigned short*)ws;
    unsigned short* Kb = (unsigned short*)(ws + QKV);
    unsigned short* Vb = (unsigned short*)(ws + 2 * QKV);
    float* tbuf = (float*)(ws + 3 * QKV);                                    // 294,912 B
    float* of   = (float*)(ws + 3 * QKV + (size_t)2 * NHEADS * SQ * sizeof(float)); // 131,072 B

    hipMemsetAsync(of, 0, (size_t)2 * 4 * SQ * sizeof(float), stream);
    prep_kernel<<<288, 256, 0, stream>>>(second_frame, first_frame, ffa,
                                         Wq, bq, Wk, bk, Wv, bv, Wt, bt,
                                         Qb, Kb, Vb, tbuf);
    dim3 ag(64, 18);
    attn_kernel<<<ag, 256, 0, stream>>>(Qb, Kb, Vb, tbuf, Wp, of);
    final_kernel<<<32, 256, 0, stream>>>(of, sff, bp, out);
}